// Round 3
// baseline (79.125 us; speedup 1.0000x reference)
//
#include <hip/hip_runtime.h>
#include <hip/hip_bf16.h>

// Exclusive prefix sum of degs -> offsets (segment start indices into idxn).
__global__ __launch_bounds__(1024) void scan_degs_kernel(
    const int* __restrict__ degs, int* __restrict__ offsets, int S) {
    const int T = 1024;
    int t = threadIdx.x;
    int chunk = (S + T - 1) / T;
    int begin = t * chunk;
    int end   = begin + chunk; if (end > S) end = S;
    if (begin > S) begin = S;

    int sum = 0;
    for (int i = begin; i < end; ++i) sum += degs[i];

    __shared__ int tmp[T];
    tmp[t] = sum;
    __syncthreads();
    int val = sum;
    for (int off = 1; off < T; off <<= 1) {
        int add = (t >= off) ? tmp[t - off] : 0;
        __syncthreads();
        val += add;
        tmp[t] = val;
        __syncthreads();
    }
    int run = val - sum;   // exclusive base for this chunk
    for (int i = begin; i < end; ++i) {
        offsets[i] = run;
        run += degs[i];
    }
}

// One WAVE per segment. Row = 128 floats = 512B = 64 lanes x float2, so one
// wave-wide dwordx2 load reads a full row coalesced. No LDS, no barriers:
// load the segment's indices into lane registers (one coalesced load),
// __shfl-broadcast each index, 4-deep unrolled row gather (4 independent
// 512B loads in flight per wave), register accumulate, scale, one 512B store.
#define WPB 4   // waves (=segments) per block

__global__ __launch_bounds__(64 * WPB) void seg_mean_wave_kernel(
    const float* __restrict__ input,
    const int*   __restrict__ idxn,
    const int*   __restrict__ offsets,
    const int*   __restrict__ degs,
    float*       __restrict__ out,
    int S) {
    int lane = threadIdx.x & 63;
    int s = blockIdx.x * WPB + (threadIdx.x >> 6);
    if (s >= S) return;

    int deg   = degs[s];
    int start = offsets[s];

    const float2* __restrict__ in2 = (const float2*)input;
    float2 a0 = make_float2(0.f, 0.f);
    float2 a1 = a0, a2 = a0, a3 = a0;

    for (int base = 0; base < deg; base += 64) {
        int cnt = deg - base; if (cnt > 64) cnt = 64;
        // one coalesced load of up to 64 indices into lane registers
        int idx_l = (lane < cnt) ? idxn[start + base + lane] : 0;

        int e = 0;
        for (; e + 3 < cnt; e += 4) {
            int r0 = __shfl(idx_l, e);
            int r1 = __shfl(idx_l, e + 1);
            int r2 = __shfl(idx_l, e + 2);
            int r3 = __shfl(idx_l, e + 3);
            float2 v0 = in2[(size_t)r0 * 64 + lane];
            float2 v1 = in2[(size_t)r1 * 64 + lane];
            float2 v2 = in2[(size_t)r2 * 64 + lane];
            float2 v3 = in2[(size_t)r3 * 64 + lane];
            a0.x += v0.x; a0.y += v0.y;
            a1.x += v1.x; a1.y += v1.y;
            a2.x += v2.x; a2.y += v2.y;
            a3.x += v3.x; a3.y += v3.y;
        }
        for (; e < cnt; ++e) {
            int r = __shfl(idx_l, e);
            float2 v = in2[(size_t)r * 64 + lane];
            a0.x += v.x; a0.y += v.y;
        }
    }

    float inv = (deg > 0) ? (1.f / (float)deg) : 0.f;
    float2 res;
    res.x = (a0.x + a1.x + a2.x + a3.x) * inv;
    res.y = (a0.y + a1.y + a2.y + a3.y) * inv;
    ((float2*)out)[(size_t)s * 64 + lane] = res;
}

// Fallback (no workspace): per-wave binary search for the segment start.
__global__ __launch_bounds__(64 * WPB) void seg_mean_wave_bs_kernel(
    const float* __restrict__ input,
    const int*   __restrict__ idxn,
    const int*   __restrict__ seg_ids,
    const int*   __restrict__ degs,
    float*       __restrict__ out,
    int E, int S) {
    int lane = threadIdx.x & 63;
    int s = blockIdx.x * WPB + (threadIdx.x >> 6);
    if (s >= S) return;

    int deg = degs[s];
    int lo = 0, hi = E;
    while (lo < hi) {
        int mid = (lo + hi) >> 1;
        if (seg_ids[mid] < s) lo = mid + 1; else hi = mid;
    }
    int start = lo;

    const float2* __restrict__ in2 = (const float2*)input;
    float2 acc = make_float2(0.f, 0.f);
    for (int base = 0; base < deg; base += 64) {
        int cnt = deg - base; if (cnt > 64) cnt = 64;
        int idx_l = (lane < cnt) ? idxn[start + base + lane] : 0;
        for (int e = 0; e < cnt; ++e) {
            int r = __shfl(idx_l, e);
            float2 v = in2[(size_t)r * 64 + lane];
            acc.x += v.x; acc.y += v.y;
        }
    }
    float inv = (deg > 0) ? (1.f / (float)deg) : 0.f;
    float2 res = make_float2(acc.x * inv, acc.y * inv);
    ((float2*)out)[(size_t)s * 64 + lane] = res;
}

extern "C" void kernel_launch(void* const* d_in, const int* in_sizes, int n_in,
                              void* d_out, int out_size, void* d_ws, size_t ws_size,
                              hipStream_t stream) {
    const float* input   = (const float*)d_in[0];
    const int*   idxn    = (const int*)d_in[1];
    const int*   seg_ids = (const int*)d_in[2];
    const int*   degs    = (const int*)d_in[3];

    int E = in_sizes[1];
    int S = in_sizes[3];
    float* out = (float*)d_out;

    int nblk = (S + WPB - 1) / WPB;
    if (ws_size >= (size_t)S * sizeof(int)) {
        int* offsets = (int*)d_ws;
        scan_degs_kernel<<<1, 1024, 0, stream>>>(degs, offsets, S);
        seg_mean_wave_kernel<<<nblk, 64 * WPB, 0, stream>>>(
            input, idxn, offsets, degs, out, S);
    } else {
        seg_mean_wave_bs_kernel<<<nblk, 64 * WPB, 0, stream>>>(
            input, idxn, seg_ids, degs, out, E, S);
    }
}

// Round 5
// 62.536 us; speedup vs baseline: 1.2653x; 1.2653x over previous
//
#include <hip/hip_runtime.h>
#include <hip/hip_bf16.h>

// Single-dispatch segment-mean gather.
// One WAVE per segment. Segment start found by wave-uniform binary search on
// sorted segment_ids (no scan kernel, no workspace). Row = 128 floats = 512B.
// Half-wave float4 gather: lanes 0-31 read row r(2i), lanes 32-63 read row
// r(2i+1) -> each load instruction moves 1024B (2 rows), 4 loads in flight
// = 8 rows/iter. Cross-half combine via __shfl_xor(...,32), then a 512B
// coalesced store from lanes 0-31.
//
// NOTE: all __shfl calls are in UNIFORM control flow (hoisted out of any
// predicated region). A __shfl whose source lane is exec-masked-off is
// undefined (ds_bpermute) — that was round 4's bug in the odd tail.
#define WPB 4   // waves (=segments) per block

__global__ __launch_bounds__(64 * WPB) void seg_mean_wave_kernel(
    const float* __restrict__ input,
    const int*   __restrict__ idxn,
    const int*   __restrict__ seg_ids,   // sorted ascending, len E
    const int*   __restrict__ degs,
    float*       __restrict__ out,
    int E, int S) {
    int tid  = threadIdx.x;
    int lane = tid & 63;
    int s    = blockIdx.x * WPB + (tid >> 6);
    if (s >= S) return;

    int deg = degs[s];

    // first edge index with seg_ids[e] >= s (wave-uniform)
    int lo = 0, hi = E;
    while (lo < hi) {
        int mid = (lo + hi) >> 1;
        if (seg_ids[mid] < s) lo = mid + 1; else hi = mid;
    }
    int start = lo;

    int half = lane >> 5;   // which row of the pair this half-wave reads
    int c4   = lane & 31;   // float4 slot within the 128-float row

    const float4* __restrict__ in4 = (const float4*)input;
    float4 a0 = make_float4(0.f, 0.f, 0.f, 0.f);
    float4 a1 = a0, a2 = a0, a3 = a0;

    for (int base = 0; base < deg; base += 64) {
        int cnt = deg - base; if (cnt > 64) cnt = 64;
        // one coalesced load of up to 64 indices into lane registers
        int idx_l = (lane < cnt) ? idxn[start + base + lane] : 0;

        int e = 0;
        // 8 rows per iteration: 4 half-wave-pair loads in flight
        for (; e + 8 <= cnt; e += 8) {
            int r0 = __shfl(idx_l, e + 0 + half);
            int r1 = __shfl(idx_l, e + 2 + half);
            int r2 = __shfl(idx_l, e + 4 + half);
            int r3 = __shfl(idx_l, e + 6 + half);
            float4 v0 = in4[(size_t)r0 * 32 + c4];
            float4 v1 = in4[(size_t)r1 * 32 + c4];
            float4 v2 = in4[(size_t)r2 * 32 + c4];
            float4 v3 = in4[(size_t)r3 * 32 + c4];
            a0.x += v0.x; a0.y += v0.y; a0.z += v0.z; a0.w += v0.w;
            a1.x += v1.x; a1.y += v1.y; a1.z += v1.z; a1.w += v1.w;
            a2.x += v2.x; a2.y += v2.y; a2.z += v2.z; a2.w += v2.w;
            a3.x += v3.x; a3.y += v3.y; a3.z += v3.z; a3.w += v3.w;
        }
        // pair tail (possibly odd). __shfl hoisted out of the predicate so
        // all 64 lanes are active when it executes; when e+half == cnt the
        // source lane holds idx_l = 0 (valid register) and the load+acc is
        // skipped by the predicate. cnt <= 63 whenever the tail runs, so
        // e+half <= cnt <= 63 is always a valid lane.
        for (; e < cnt; e += 2) {
            int r = __shfl(idx_l, e + half);
            if (e + half < cnt) {
                float4 v = in4[(size_t)r * 32 + c4];
                a0.x += v.x; a0.y += v.y; a0.z += v.z; a0.w += v.w;
            }
        }
    }

    a0.x += a1.x + a2.x + a3.x;
    a0.y += a1.y + a2.y + a3.y;
    a0.z += a1.z + a2.z + a3.z;
    a0.w += a1.w + a2.w + a3.w;

    // combine the two half-wave partials (lane l <-> lane l^32)
    a0.x += __shfl_xor(a0.x, 32);
    a0.y += __shfl_xor(a0.y, 32);
    a0.z += __shfl_xor(a0.z, 32);
    a0.w += __shfl_xor(a0.w, 32);

    if (half == 0) {
        float inv = (deg > 0) ? (1.f / (float)deg) : 0.f;
        float4 res = make_float4(a0.x * inv, a0.y * inv, a0.z * inv, a0.w * inv);
        ((float4*)out)[(size_t)s * 32 + c4] = res;
    }
}

extern "C" void kernel_launch(void* const* d_in, const int* in_sizes, int n_in,
                              void* d_out, int out_size, void* d_ws, size_t ws_size,
                              hipStream_t stream) {
    const float* input   = (const float*)d_in[0];
    const int*   idxn    = (const int*)d_in[1];
    const int*   seg_ids = (const int*)d_in[2];
    const int*   degs    = (const int*)d_in[3];

    int E = in_sizes[1];
    int S = in_sizes[3];
    float* out = (float*)d_out;

    int nblk = (S + WPB - 1) / WPB;
    seg_mean_wave_kernel<<<nblk, 64 * WPB, 0, stream>>>(
        input, idxn, seg_ids, degs, out, E, S);
}